// Round 7
// baseline (1110.164 us; speedup 1.0000x reference)
//
#include <hip/hip_runtime.h>

// SimpleSelfAttention: B=16, S=2048, E=1024, fp32 in/out.
// out[b] = mean_q softmax(QK^T/32)·V == (Σ_k w[b,k]·x[b,k,:]) @ Wv^T + bv.
// Softmax shift-invariance: QK^T ≡ x·(Wq^T·Wk)·x^T + 1·v^T, v = x·(Wk^T·bq).
// R6: gemm_mx_exp at __launch_bounds__(256,3) — between R4's 128-VGPR spill
// cliff and R5's 232-VGPR/1-block-CU occupancy collapse. Live set ~135 VGPR
// (acc 64 + bfv 32 + af 8 + addr) fits the ~170 cap; 3 blocks/CU restores
// the m97 overlap regime.

#define B_ 16
#define S_ 2048
#define E_ 1024

typedef __bf16 bf16x8 __attribute__((ext_vector_type(8)));
typedef float f32x4 __attribute__((ext_vector_type(4)));
typedef float f32x2 __attribute__((ext_vector_type(2)));
typedef int i32x8 __attribute__((ext_vector_type(8)));

__device__ __forceinline__ unsigned short f2bf(float f) {
  unsigned int u = __float_as_uint(f);
  u = (u + 0x7FFFu + ((u >> 16) & 1u)) >> 16;  // RNE; finite inputs
  return (unsigned short)u;
}

// ---- g[e] = Σ_f wk[f,e]·bq[f] ---------------------------------------------
__global__ __launch_bounds__(256) void gvec_kernel(
    const float* __restrict__ wk, const float* __restrict__ bq,
    float* __restrict__ g) {
  const int e = blockIdx.x * 256 + threadIdx.x;
  const int f0 = blockIdx.y * 32;
  float acc = 0.f;
#pragma unroll
  for (int i = 0; i < 32; ++i) acc += wk[(size_t)(f0 + i) * E_ + e] * bq[f0 + i];
  atomicAdd(&g[e], acc);
}

// ---- cast x->bf16; x->fp8 (π-permuted cols); vs[row] = (x·g)/32 -----------
// π: true col c = g*64 + ni*16 + lr  ->  stored byte g*64 + lr*4 + ni.
__global__ __launch_bounds__(256) void cast_x_v_kernel(
    const float* __restrict__ x, const float* __restrict__ g,
    unsigned short* __restrict__ xbf, unsigned int* __restrict__ xf8,
    float* __restrict__ vs) {
  const int row = blockIdx.x, t = threadIdx.x;
  const size_t i = (size_t)row * E_ + t * 4;
  float4 v = *(const float4*)(x + i);
  float4 gv = *(const float4*)(g + t * 4);
  ushort4 o;
  o.x = f2bf(v.x); o.y = f2bf(v.y); o.z = f2bf(v.z); o.w = f2bf(v.w);
  *(ushort4*)(xbf + i) = o;
  // fp8 permuted store: thread t = grp*16 + lr handles cols grp*64+lr+16*ni
  {
    const int grp = t >> 4, lr = t & 15;
    const float* xr = x + (size_t)row * E_ + grp * 64 + lr;
    unsigned int pk = 0;
    pk = __builtin_amdgcn_cvt_pk_fp8_f32(xr[0], xr[16], pk, false);
    pk = __builtin_amdgcn_cvt_pk_fp8_f32(xr[32], xr[48], pk, true);
    xf8[(size_t)row * (E_ / 4) + t] = pk;
  }
  float p = v.x * gv.x + v.y * gv.y + v.z * gv.z + v.w * gv.w;
#pragma unroll
  for (int off = 32; off >= 1; off >>= 1) p += __shfl_xor(p, off);
  __shared__ float wsp[4];
  if ((t & 63) == 0) wsp[t >> 6] = p;
  __syncthreads();
  if (t == 0) vs[row] = (wsp[0] + wsp[1] + wsp[2] + wsp[3]) * 0.03125f;
}

// ---- transpose-cast: dst[e,f] = bf16(src[f,e]), 1024x1024 -----------------
__global__ __launch_bounds__(256) void tcast_kernel(
    const float* __restrict__ src, unsigned short* __restrict__ dst) {
  __shared__ float tile[32][33];
  const int tx = threadIdx.x & 31, ty = threadIdx.x >> 5;
  const int f0 = blockIdx.y * 32, e0 = blockIdx.x * 32;
#pragma unroll
  for (int j = 0; j < 4; ++j)
    tile[ty + 8 * j][tx] = src[(size_t)(f0 + ty + 8 * j) * E_ + e0 + tx];
  __syncthreads();
#pragma unroll
  for (int j = 0; j < 4; ++j)
    dst[(size_t)(e0 + ty + 8 * j) * E_ + f0 + tx] = f2bf(tile[tx][ty + 8 * j]);
}

// ---- bf16 MFMA GEMM (128x128, BK=64, 16x16x32) ----------------------------
// MODE 0: C(bf16) = A·B^T   (used for Mt)
// MODE 2: C(fp8, π-permuted packed dwords) = A·B^T  (used for y)
template <int MODE>
__global__ __launch_bounds__(256, 2) void gemm_bt(
    const unsigned short* __restrict__ A, const unsigned short* __restrict__ Bm,
    void* __restrict__ Cout, int K, int lda, int ldb, int ldc) {
  __shared__ unsigned short As[128 * 64];
  __shared__ unsigned short Bs[128 * 64];
  const int tid = threadIdx.x, wave = tid >> 6, lane = tid & 63;
  const int rowBase = blockIdx.y * 128, colBase = blockIdx.x * 128;
  const int waveM = wave >> 1, waveN = wave & 1;
  const int lrow = lane & 15, lq = lane >> 4;
  const int rsub = lane >> 3;
  const int gOff = (((lane & 7) ^ rsub) << 3);

  f32x4 acc[4][4];
#pragma unroll
  for (int i = 0; i < 4; ++i)
#pragma unroll
    for (int j = 0; j < 4; ++j) {
      f32x4 z = {0.f, 0.f, 0.f, 0.f};
      acc[i][j] = z;
    }

  for (int k0 = 0; k0 < K; k0 += 64) {
#pragma unroll
    for (int i = 0; i < 4; ++i) {
      const int chunk = wave * 4 + i;
      const int r = chunk * 8 + rsub;
      const unsigned short* ga = A + (size_t)(rowBase + r) * lda + (k0 + gOff);
      const unsigned short* gb = Bm + (size_t)(colBase + r) * ldb + (k0 + gOff);
      __builtin_amdgcn_global_load_lds(
          (const __attribute__((address_space(1))) void*)ga,
          (__attribute__((address_space(3))) void*)(&As[chunk * 512]), 16, 0, 0);
      __builtin_amdgcn_global_load_lds(
          (const __attribute__((address_space(1))) void*)gb,
          (__attribute__((address_space(3))) void*)(&Bs[chunk * 512]), 16, 0, 0);
    }
    __syncthreads();
#pragma unroll
    for (int ks = 0; ks < 2; ++ks) {
      const int gg = (((ks * 4 + lq) ^ (lrow & 7)) << 3);
      bf16x8 af[4], bfv[4];
#pragma unroll
      for (int mi = 0; mi < 4; ++mi)
        af[mi] = *(const bf16x8*)(&As[(waveM * 64 + mi * 16 + lrow) * 64 + gg]);
#pragma unroll
      for (int ni = 0; ni < 4; ++ni)
        bfv[ni] = *(const bf16x8*)(&Bs[(waveN * 64 + ni * 16 + lrow) * 64 + gg]);
#pragma unroll
      for (int mi = 0; mi < 4; ++mi)
#pragma unroll
        for (int ni = 0; ni < 4; ++ni)
          acc[mi][ni] = __builtin_amdgcn_mfma_f32_16x16x32_bf16(
              af[mi], bfv[ni], acc[mi][ni], 0, 0, 0);
    }
    __syncthreads();
  }

  if constexpr (MODE == 0) {
    unsigned short* Cb = (unsigned short*)Cout;
#pragma unroll
    for (int mi = 0; mi < 4; ++mi) {
      const int grow = rowBase + waveM * 64 + mi * 16 + lq * 4;
#pragma unroll
      for (int ni = 0; ni < 4; ++ni) {
        const int gcol = colBase + waveN * 64 + ni * 16 + lrow;
#pragma unroll
        for (int r = 0; r < 4; ++r)
          Cb[(size_t)(grow + r) * ldc + gcol] = f2bf(acc[mi][ni][r]);
      }
    }
  } else {  // fp8, π-permuted packed dword per (row, 64-col group)
    unsigned int* Cd = (unsigned int*)Cout;
    const int dbase = (colBase + waveN * 64) >> 2;
#pragma unroll
    for (int mi = 0; mi < 4; ++mi) {
      const int grow = rowBase + waveM * 64 + mi * 16 + lq * 4;
#pragma unroll
      for (int r = 0; r < 4; ++r) {
        unsigned int pk = 0;
        pk = __builtin_amdgcn_cvt_pk_fp8_f32(acc[mi][0][r], acc[mi][1][r], pk,
                                             false);
        pk = __builtin_amdgcn_cvt_pk_fp8_f32(acc[mi][2][r], acc[mi][3][r], pk,
                                             true);
        Cd[(size_t)(grow + r) * (ldc >> 2) + dbase + lrow] = pk;
      }
    }
  }
}

// ---- MX-fp8 scores GEMM: e = exp(A·B^T/32 + vs[col]), fp8 store, rowsum ---
// A=yf8, B=xf8 (both π-col-permuted, row stride E_ bytes), 128x128 tile,
// BK=128 B, mfma_scale_f32_16x16x128_f8f6f4 with unit scales (0x7F = 2^0).
// (256,3): ~170 VGPR cap — fits the ~135-reg live set, 3 blocks/CU.
__global__ __launch_bounds__(256, 3) void gemm_mx_exp(
    const unsigned char* __restrict__ A, const unsigned char* __restrict__ Bm,
    unsigned char* __restrict__ Eout, const float* __restrict__ vs,
    float* __restrict__ rowsum, float scale) {
  __shared__ __align__(16) unsigned char As[128 * 128];  // 16 KB
  __shared__ __align__(16) unsigned char Bs[128 * 128];  // 16 KB
  const int tid = threadIdx.x, wave = tid >> 6, lane = tid & 63;
  const int bz = blockIdx.z;
  const unsigned char* Ab = A + (size_t)bz * S_ * E_;
  const unsigned char* Bb = Bm + (size_t)bz * S_ * E_;
  const int rowBase = blockIdx.y * 128, colBase = blockIdx.x * 128;
  const int waveM = wave >> 1, waveN = wave & 1;
  const int lrow = lane & 15, quad = lane >> 4;
  const int rsub = lane >> 3;
  const int gOff = (((lane & 7) ^ rsub) << 4);  // byte offset in 128-B row

  f32x4 acc[4][4];
#pragma unroll
  for (int i = 0; i < 4; ++i)
#pragma unroll
    for (int j = 0; j < 4; ++j) {
      f32x4 z = {0.f, 0.f, 0.f, 0.f};
      acc[i][j] = z;
    }

  const int p0 = ((2 * quad) ^ (lrow & 7)) << 4;
  const int p1 = ((2 * quad + 1) ^ (lrow & 7)) << 4;

  for (int k0 = 0; k0 < E_; k0 += 128) {
#pragma unroll
    for (int i = 0; i < 4; ++i) {
      const int chunk = wave * 4 + i;
      const int r = chunk * 8 + rsub;
      const unsigned char* ga = Ab + (size_t)(rowBase + r) * E_ + k0 + gOff;
      const unsigned char* gb = Bb + (size_t)(colBase + r) * E_ + k0 + gOff;
      __builtin_amdgcn_global_load_lds(
          (const __attribute__((address_space(1))) void*)ga,
          (__attribute__((address_space(3))) void*)(&As[chunk * 1024]), 16, 0,
          0);
      __builtin_amdgcn_global_load_lds(
          (const __attribute__((address_space(1))) void*)gb,
          (__attribute__((address_space(3))) void*)(&Bs[chunk * 1024]), 16, 0,
          0);
    }
    __syncthreads();

    // B fragments resident (32 VGPRs); A fragment streamed per-mi (8 VGPRs).
    i32x8 bfv[4];
#pragma unroll
    for (int ni = 0; ni < 4; ++ni) {
      const int r = waveN * 64 + ni * 16 + lrow;
      *(int4*)(&bfv[ni]) = *(const int4*)(&Bs[r * 128 + p0]);
      *((int4*)(&bfv[ni]) + 1) = *(const int4*)(&Bs[r * 128 + p1]);
    }
#pragma unroll
    for (int mi = 0; mi < 4; ++mi) {
      const int r = waveM * 64 + mi * 16 + lrow;
      i32x8 af;
      *(int4*)(&af) = *(const int4*)(&As[r * 128 + p0]);
      *((int4*)(&af) + 1) = *(const int4*)(&As[r * 128 + p1]);
#pragma unroll
      for (int ni = 0; ni < 4; ++ni)
        acc[mi][ni] = __builtin_amdgcn_mfma_scale_f32_16x16x128_f8f6f4(
            af, bfv[ni], acc[mi][ni], 0, 0, 0, 0x7F7F7F7F, 0, 0x7F7F7F7F);
    }
    __syncthreads();
  }

  // epilogue: col=lane&15, row=quad*4+reg; exp + fp8 permuted store + rowsum
  unsigned char* Eb = Eout + (size_t)bz * S_ * S_;
  float* rs = rowsum + (size_t)bz * S_;
  const float* vsb = vs + (size_t)bz * S_;
  float badd[4];
#pragma unroll
  for (int ni = 0; ni < 4; ++ni)
    badd[ni] = vsb[colBase + waveN * 64 + ni * 16 + lrow];
#pragma unroll
  for (int mi = 0; mi < 4; ++mi) {
    const int grow = rowBase + waveM * 64 + mi * 16 + quad * 4;
#pragma unroll
    for (int r = 0; r < 4; ++r) {
      float e[4];
      float partial = 0.f;
#pragma unroll
      for (int ni = 0; ni < 4; ++ni) {
        e[ni] = __expf(acc[mi][ni][r] * scale + badd[ni]);
        partial += e[ni];
      }
      unsigned int pk = 0;
      pk = __builtin_amdgcn_cvt_pk_fp8_f32(e[0], e[1], pk, false);
      pk = __builtin_amdgcn_cvt_pk_fp8_f32(e[2], e[3], pk, true);
      *(unsigned int*)(&Eb[(size_t)(grow + r) * S_ + colBase + waveN * 64 +
                           lrow * 4]) = pk;
      partial += __shfl_xor(partial, 1);
      partial += __shfl_xor(partial, 2);
      partial += __shfl_xor(partial, 4);
      partial += __shfl_xor(partial, 8);
      if (lrow == 0) atomicAdd(&rs[grow + r], partial);
    }
  }
}

// ---- wsum[k] = (1/S)·Σ_q e[q,k]/rowsum[q]; fp8 input, permuted cols -------
__global__ __launch_bounds__(256) void colsum_kernel(
    const unsigned int* __restrict__ Epk, const float* __restrict__ rowsum,
    float* __restrict__ wsum) {
  const int b = blockIdx.y, q0 = blockIdx.x * 64, t = threadIdx.x;
  __shared__ float rinv[64];
  if (t < 64) rinv[t] = 1.0f / rowsum[(size_t)b * S_ + q0 + t];
  __syncthreads();
  float cs[2][4] = {{0, 0, 0, 0}, {0, 0, 0, 0}};
  const unsigned int* Eb = Epk + ((size_t)b * S_ + q0) * (S_ / 4);
  for (int q = 0; q < 64; ++q) {
    const float rv = rinv[q];
    const unsigned int* row = Eb + (size_t)q * (S_ / 4);
#pragma unroll
    for (int j = 0; j < 2; ++j) {
      const unsigned int p = row[t + 256 * j];
      f32x2 lo = __builtin_amdgcn_cvt_pk_f32_fp8(p, false);
      f32x2 hi = __builtin_amdgcn_cvt_pk_f32_fp8(p, true);
      cs[j][0] += lo[0] * rv;
      cs[j][1] += lo[1] * rv;
      cs[j][2] += hi[0] * rv;
      cs[j][3] += hi[1] * rv;
    }
  }
  const float inv = 1.0f / (float)S_;
#pragma unroll
  for (int j = 0; j < 2; ++j) {
    const int d = t + 256 * j;
    const int base = (d >> 4) * 64 + (d & 15);
#pragma unroll
    for (int jj = 0; jj < 4; ++jj)
      atomicAdd(&wsum[(size_t)b * S_ + base + 16 * jj], cs[j][jj] * inv);
  }
}

// ---- xbar[b,e] = Σ_k wsum[b,k]·xbf[b,k,e]  (bf16 x) -----------------------
__global__ __launch_bounds__(256) void xbar_kernel(
    const unsigned short* __restrict__ xbf, const float* __restrict__ wsum,
    float* __restrict__ xbar) {
  const int b = blockIdx.y, kc = blockIdx.x, t = threadIdx.x;
  float4 acc = {0.f, 0.f, 0.f, 0.f};
  for (int k0 = 0; k0 < 128; ++k0) {
    const int k = kc * 128 + k0;
    const float w = wsum[(size_t)b * S_ + k];
    const ushort4 xv =
        *(const ushort4*)(xbf + ((size_t)b * S_ + k) * E_ + t * 4);
    acc.x += w * __uint_as_float((unsigned int)xv.x << 16);
    acc.y += w * __uint_as_float((unsigned int)xv.y << 16);
    acc.z += w * __uint_as_float((unsigned int)xv.z << 16);
    acc.w += w * __uint_as_float((unsigned int)xv.w << 16);
  }
  float* xb = xbar + (size_t)b * E_ + t * 4;
  atomicAdd(&xb[0], acc.x);
  atomicAdd(&xb[1], acc.y);
  atomicAdd(&xb[2], acc.z);
  atomicAdd(&xb[3], acc.w);
}

// ---- out[b,e] += Σ_{chunk} xbar[b,c]·wv[e,c] (+bv on chunk 0) -------------
__global__ __launch_bounds__(256) void out_kernel(
    const float* __restrict__ xbar, const float* __restrict__ wv,
    const float* __restrict__ bv, float* __restrict__ out) {
  const int gid = blockIdx.x * 256 + threadIdx.x;
  const int b = gid >> 10, e = gid & 1023;
  const int c0 = blockIdx.y * 64;
  const float4* xr = (const float4*)(xbar + (size_t)b * E_) + c0;
  const float4* wr = (const float4*)(wv + (size_t)e * E_) + c0;
  float s = 0.f;
  for (int j = 0; j < 64; ++j) {
    float4 a = xr[j], w = wr[j];
    s += a.x * w.x + a.y * w.y + a.z * w.z + a.w * w.w;
  }
  if (blockIdx.y == 0) s += bv[e];
  atomicAdd(&out[gid], s);
}

extern "C" void kernel_launch(void* const* d_in, const int* in_sizes, int n_in,
                              void* d_out, int out_size, void* d_ws,
                              size_t ws_size, hipStream_t stream) {
  const float* x = (const float*)d_in[0];
  const float* wq = (const float*)d_in[1];
  const float* bq = (const float*)d_in[2];
  const float* wk = (const float*)d_in[3];
  // bk cancels in softmax
  const float* wv = (const float*)d_in[5];
  const float* bv = (const float*)d_in[6];
  float* out = (float*)d_out;

  char* ws = (char*)d_ws;
  const size_t MB = 1ull << 20;
  // xbf(64MB) | yf8(32MB) | Ebuf(64MB) | xf8(32MB) | WqT(2) | WkT(2) | Mt(2)
  // | Z: g(4KB) rowsum(128KB) wsum(128KB) xbar(64KB) | vs(128KB)
  unsigned short* xbf = (unsigned short*)(ws);
  unsigned char* yf8 = (unsigned char*)(ws + 64 * MB);
  unsigned char* Ebuf = (unsigned char*)(ws + 96 * MB);
  unsigned int* xf8 = (unsigned int*)(ws + 160 * MB);
  unsigned short* WqT = (unsigned short*)(ws + 192 * MB);
  unsigned short* WkT = (unsigned short*)(ws + 194 * MB);
  unsigned short* Mt = (unsigned short*)(ws + 196 * MB);
  float* g = (float*)(ws + 198 * MB);
  float* rowsum = g + E_;
  float* wsum = rowsum + B_ * S_;
  float* xbar = wsum + B_ * S_;
  float* vs = xbar + B_ * E_;

  hipMemsetAsync(g, 0, (size_t)(E_ + 2 * B_ * S_ + B_ * E_) * sizeof(float),
                 stream);
  hipMemsetAsync(out, 0, (size_t)B_ * E_ * sizeof(float), stream);

  gvec_kernel<<<dim3(E_ / 256, 32), 256, 0, stream>>>(wk, bq, g);
  cast_x_v_kernel<<<B_ * S_, 256, 0, stream>>>(x, g, xbf, xf8, vs);
  tcast_kernel<<<dim3(32, 32), 256, 0, stream>>>(wq, WqT);
  tcast_kernel<<<dim3(32, 32), 256, 0, stream>>>(wk, WkT);

  // Mt[e',e] = Σ_f wk[f,e']·wq[f,e]  (bf16 out)
  gemm_bt<0><<<dim3(8, 8), 256, 0, stream>>>(WkT, WqT, (void*)Mt, E_, E_, E_,
                                             E_);
  // y = x·M  -> fp8, π-permuted columns
  gemm_bt<2><<<dim3(E_ / 128, (B_ * S_) / 128), 256, 0, stream>>>(
      xbf, Mt, (void*)yf8, E_, E_, E_, E_);
  // e[b,q,k] = exp(y_q·x_k/32 + vs[b,k]) -> fp8; rowsum fp32
  gemm_mx_exp<<<dim3(S_ / 128, S_ / 128, B_), 256, 0, stream>>>(
      yf8, (const unsigned char*)xf8, Ebuf, vs, rowsum, 0.03125f);

  colsum_kernel<<<dim3(S_ / 64, B_), 256, 0, stream>>>(
      (const unsigned int*)Ebuf, rowsum, wsum);
  xbar_kernel<<<dim3(16, B_), 256, 0, stream>>>(xbf, wsum, xbar);
  out_kernel<<<dim3(B_ * E_ / 256, 4), 256, 0, stream>>>(xbar, wv, bv, out);
}

// Round 8
// 502.199 us; speedup vs baseline: 2.2106x; 2.2106x over previous
//
#include <hip/hip_runtime.h>

// SimpleSelfAttention: B=16, S=2048, E=1024, fp32 in/out.
// out[b] = mean_q softmax(QK^T/32)·V == (Σ_k w[b,k]·x[b,k,:]) @ Wv^T + bv.
// Softmax shift-invariance: QK^T ≡ x·(Wq^T·Wk)·x^T + 1·v^T, v = x·(Wk^T·bq).
// R7: revert scores GEMM to the proven bf16 MFMA path (147 µs; MX attempts
// R4-R6 hit compiler reg-alloc cliffs: cap128=spill, cap84=worse, 232=1 wave/
// SIMD => best MX 206 µs). Keep: fp8 π-permuted e-store, fp8 colsum, bf16
// xbar, split-E out.

#define B_ 16
#define S_ 2048
#define E_ 1024

typedef __bf16 bf16x8 __attribute__((ext_vector_type(8)));
typedef float f32x4 __attribute__((ext_vector_type(4)));
typedef float f32x2 __attribute__((ext_vector_type(2)));

__device__ __forceinline__ unsigned short f2bf(float f) {
  unsigned int u = __float_as_uint(f);
  u = (u + 0x7FFFu + ((u >> 16) & 1u)) >> 16;  // RNE; finite inputs
  return (unsigned short)u;
}

// ---- g[e] = Σ_f wk[f,e]·bq[f] ---------------------------------------------
__global__ __launch_bounds__(256) void gvec_kernel(
    const float* __restrict__ wk, const float* __restrict__ bq,
    float* __restrict__ g) {
  const int e = blockIdx.x * 256 + threadIdx.x;
  const int f0 = blockIdx.y * 32;
  float acc = 0.f;
#pragma unroll
  for (int i = 0; i < 32; ++i) acc += wk[(size_t)(f0 + i) * E_ + e] * bq[f0 + i];
  atomicAdd(&g[e], acc);
}

// ---- cast x -> bf16 AND vs[row] = (x_row · g)/32 ; block == one row -------
__global__ __launch_bounds__(256) void cast_x_v_kernel(
    const float* __restrict__ x, const float* __restrict__ g,
    unsigned short* __restrict__ xbf, float* __restrict__ vs) {
  const int row = blockIdx.x, t = threadIdx.x;
  const size_t i = (size_t)row * E_ + t * 4;
  float4 v = *(const float4*)(x + i);
  float4 gv = *(const float4*)(g + t * 4);
  ushort4 o;
  o.x = f2bf(v.x); o.y = f2bf(v.y); o.z = f2bf(v.z); o.w = f2bf(v.w);
  *(ushort4*)(xbf + i) = o;
  float p = v.x * gv.x + v.y * gv.y + v.z * gv.z + v.w * gv.w;
#pragma unroll
  for (int off = 32; off >= 1; off >>= 1) p += __shfl_xor(p, off);
  __shared__ float wsp[4];
  if ((t & 63) == 0) wsp[t >> 6] = p;
  __syncthreads();
  if (t == 0) vs[row] = (wsp[0] + wsp[1] + wsp[2] + wsp[3]) * 0.03125f;
}

// ---- transpose-cast: dst[e,f] = bf16(src[f,e]), 1024x1024 -----------------
__global__ __launch_bounds__(256) void tcast_kernel(
    const float* __restrict__ src, unsigned short* __restrict__ dst) {
  __shared__ float tile[32][33];
  const int tx = threadIdx.x & 31, ty = threadIdx.x >> 5;
  const int f0 = blockIdx.y * 32, e0 = blockIdx.x * 32;
#pragma unroll
  for (int j = 0; j < 4; ++j)
    tile[ty + 8 * j][tx] = src[(size_t)(f0 + ty + 8 * j) * E_ + e0 + tx];
  __syncthreads();
#pragma unroll
  for (int j = 0; j < 4; ++j)
    dst[(size_t)(e0 + ty + 8 * j) * E_ + f0 + tx] = f2bf(tile[tx][ty + 8 * j]);
}

// ---- bf16 MFMA GEMM, 128x128 tile, BK=64, 4 waves, 16x16x32 MFMA ----------
// MODE 0: C(bf16) = A·B^T            (Mt, y — no bias)
// MODE 1: e = exp(A·B^T·scale + vs[bz*S+col]); fp8-e4m3 π-permuted packed
//         store (dword per (row, 64-col grp): byte ni -> col grp*64+16ni+lr);
//         fp32 rowsum via 16-lane shfl + atomic.
template <int MODE>
__global__ __launch_bounds__(256, 2) void gemm_bt(
    const unsigned short* __restrict__ A, const unsigned short* __restrict__ Bm,
    void* __restrict__ Cout, const float* __restrict__ vs,
    float* __restrict__ rowsum, float scale,
    int K, int lda, int ldb, int ldc,
    long long strideA, long long strideB, long long strideC) {
  __shared__ unsigned short As[128 * 64];  // 16 KB
  __shared__ unsigned short Bs[128 * 64];  // 16 KB

  const int tid = threadIdx.x;
  const int wave = tid >> 6;
  const int lane = tid & 63;
  const int bz = blockIdx.z;
  const unsigned short* Ab = A + (size_t)bz * strideA;
  const unsigned short* Bb = Bm + (size_t)bz * strideB;
  const int rowBase = blockIdx.y * 128;
  const int colBase = blockIdx.x * 128;

  const int waveM = wave >> 1, waveN = wave & 1;
  const int lrow = lane & 15, lq = lane >> 4;

  const int rsub = lane >> 3;                   // row within 8-row chunk
  const int gOff = (((lane & 7) ^ rsub) << 3);  // swizzled source granule

  f32x4 acc[4][4];
#pragma unroll
  for (int i = 0; i < 4; ++i)
#pragma unroll
    for (int j = 0; j < 4; ++j) {
      f32x4 z = {0.f, 0.f, 0.f, 0.f};
      acc[i][j] = z;
    }

  for (int k0 = 0; k0 < K; k0 += 64) {
#pragma unroll
    for (int i = 0; i < 4; ++i) {
      const int chunk = wave * 4 + i;
      const int r = chunk * 8 + rsub;
      const unsigned short* ga = Ab + (size_t)(rowBase + r) * lda + (k0 + gOff);
      const unsigned short* gb = Bb + (size_t)(colBase + r) * ldb + (k0 + gOff);
      __builtin_amdgcn_global_load_lds(
          (const __attribute__((address_space(1))) void*)ga,
          (__attribute__((address_space(3))) void*)(&As[chunk * 512]), 16, 0, 0);
      __builtin_amdgcn_global_load_lds(
          (const __attribute__((address_space(1))) void*)gb,
          (__attribute__((address_space(3))) void*)(&Bs[chunk * 512]), 16, 0, 0);
    }
    __syncthreads();

#pragma unroll
    for (int ks = 0; ks < 2; ++ks) {
      const int gg = (((ks * 4 + lq) ^ (lrow & 7)) << 3);
      bf16x8 af[4], bfv[4];
#pragma unroll
      for (int mi = 0; mi < 4; ++mi)
        af[mi] = *(const bf16x8*)(&As[(waveM * 64 + mi * 16 + lrow) * 64 + gg]);
#pragma unroll
      for (int ni = 0; ni < 4; ++ni)
        bfv[ni] = *(const bf16x8*)(&Bs[(waveN * 64 + ni * 16 + lrow) * 64 + gg]);
#pragma unroll
      for (int mi = 0; mi < 4; ++mi)
#pragma unroll
        for (int ni = 0; ni < 4; ++ni)
          acc[mi][ni] = __builtin_amdgcn_mfma_f32_16x16x32_bf16(
              af[mi], bfv[ni], acc[mi][ni], 0, 0, 0);
    }
    __syncthreads();
  }

  // epilogue: C/D layout col=lane&15, row=(lane>>4)*4+reg  [m89-verified]
  if constexpr (MODE == 0) {
    unsigned short* Cb = (unsigned short*)Cout;
#pragma unroll
    for (int mi = 0; mi < 4; ++mi) {
      const int grow = rowBase + waveM * 64 + mi * 16 + lq * 4;
#pragma unroll
      for (int ni = 0; ni < 4; ++ni) {
        const int gcol = colBase + waveN * 64 + ni * 16 + lrow;
#pragma unroll
        for (int r = 0; r < 4; ++r)
          Cb[(size_t)(grow + r) * ldc + gcol] = f2bf(acc[mi][ni][r]);
      }
    }
  } else {
    unsigned char* Eb = (unsigned char*)Cout + (size_t)bz * strideC;
    float* rs = rowsum + (size_t)bz * S_;
    const float* vsb = vs + (size_t)bz * S_;
    float badd[4];
#pragma unroll
    for (int ni = 0; ni < 4; ++ni)
      badd[ni] = vsb[colBase + waveN * 64 + ni * 16 + lrow];
#pragma unroll
    for (int mi = 0; mi < 4; ++mi) {
      const int grow = rowBase + waveM * 64 + mi * 16 + lq * 4;
#pragma unroll
      for (int r = 0; r < 4; ++r) {
        float e[4];
        float partial = 0.f;
#pragma unroll
        for (int ni = 0; ni < 4; ++ni) {
          e[ni] = __expf(acc[mi][ni][r] * scale + badd[ni]);
          partial += e[ni];
        }
        unsigned int pk = 0;
        pk = __builtin_amdgcn_cvt_pk_fp8_f32(e[0], e[1], pk, false);
        pk = __builtin_amdgcn_cvt_pk_fp8_f32(e[2], e[3], pk, true);
        *(unsigned int*)(&Eb[(size_t)(grow + r) * S_ + colBase + waveN * 64 +
                             lrow * 4]) = pk;
        partial += __shfl_xor(partial, 1);
        partial += __shfl_xor(partial, 2);
        partial += __shfl_xor(partial, 4);
        partial += __shfl_xor(partial, 8);
        if (lrow == 0) atomicAdd(&rs[grow + r], partial);
      }
    }
  }
}

// ---- wsum[k] = (1/S)·Σ_q e[q,k]/rowsum[q]; fp8 input, permuted cols -------
// dword d of a row: byte jj -> true col (d>>4)*64 + (d&15) + 16*jj.
__global__ __launch_bounds__(256) void colsum_kernel(
    const unsigned int* __restrict__ Epk, const float* __restrict__ rowsum,
    float* __restrict__ wsum) {
  const int b = blockIdx.y, q0 = blockIdx.x * 64, t = threadIdx.x;
  __shared__ float rinv[64];
  if (t < 64) rinv[t] = 1.0f / rowsum[(size_t)b * S_ + q0 + t];
  __syncthreads();
  float cs[2][4] = {{0, 0, 0, 0}, {0, 0, 0, 0}};
  const unsigned int* Eb = Epk + ((size_t)b * S_ + q0) * (S_ / 4);
  for (int q = 0; q < 64; ++q) {
    const float rv = rinv[q];
    const unsigned int* row = Eb + (size_t)q * (S_ / 4);
#pragma unroll
    for (int j = 0; j < 2; ++j) {
      const unsigned int p = row[t + 256 * j];
      f32x2 lo = __builtin_amdgcn_cvt_pk_f32_fp8(p, false);
      f32x2 hi = __builtin_amdgcn_cvt_pk_f32_fp8(p, true);
      cs[j][0] += lo[0] * rv;
      cs[j][1] += lo[1] * rv;
      cs[j][2] += hi[0] * rv;
      cs[j][3] += hi[1] * rv;
    }
  }
  const float inv = 1.0f / (float)S_;
#pragma unroll
  for (int j = 0; j < 2; ++j) {
    const int d = t + 256 * j;
    const int base = (d >> 4) * 64 + (d & 15);
#pragma unroll
    for (int jj = 0; jj < 4; ++jj)
      atomicAdd(&wsum[(size_t)b * S_ + base + 16 * jj], cs[j][jj] * inv);
  }
}

// ---- xbar[b,e] = Σ_k wsum[b,k]·xbf[b,k,e]  (bf16 x) -----------------------
__global__ __launch_bounds__(256) void xbar_kernel(
    const unsigned short* __restrict__ xbf, const float* __restrict__ wsum,
    float* __restrict__ xbar) {
  const int b = blockIdx.y, kc = blockIdx.x, t = threadIdx.x;
  float4 acc = {0.f, 0.f, 0.f, 0.f};
  for (int k0 = 0; k0 < 128; ++k0) {
    const int k = kc * 128 + k0;
    const float w = wsum[(size_t)b * S_ + k];
    const ushort4 xv =
        *(const ushort4*)(xbf + ((size_t)b * S_ + k) * E_ + t * 4);
    acc.x += w * __uint_as_float((unsigned int)xv.x << 16);
    acc.y += w * __uint_as_float((unsigned int)xv.y << 16);
    acc.z += w * __uint_as_float((unsigned int)xv.z << 16);
    acc.w += w * __uint_as_float((unsigned int)xv.w << 16);
  }
  float* xb = xbar + (size_t)b * E_ + t * 4;
  atomicAdd(&xb[0], acc.x);
  atomicAdd(&xb[1], acc.y);
  atomicAdd(&xb[2], acc.z);
  atomicAdd(&xb[3], acc.w);
}

// ---- out[b,e] += Σ_{chunk} xbar[b,c]·wv[e,c] (+bv on chunk 0) -------------
__global__ __launch_bounds__(256) void out_kernel(
    const float* __restrict__ xbar, const float* __restrict__ wv,
    const float* __restrict__ bv, float* __restrict__ out) {
  const int gid = blockIdx.x * 256 + threadIdx.x;
  const int b = gid >> 10, e = gid & 1023;
  const int c0 = blockIdx.y * 64;
  const float4* xr = (const float4*)(xbar + (size_t)b * E_) + c0;
  const float4* wr = (const float4*)(wv + (size_t)e * E_) + c0;
  float s = 0.f;
  for (int j = 0; j < 64; ++j) {
    float4 a = xr[j], w = wr[j];
    s += a.x * w.x + a.y * w.y + a.z * w.z + a.w * w.w;
  }
  if (blockIdx.y == 0) s += bv[e];
  atomicAdd(&out[gid], s);
}

extern "C" void kernel_launch(void* const* d_in, const int* in_sizes, int n_in,
                              void* d_out, int out_size, void* d_ws,
                              size_t ws_size, hipStream_t stream) {
  const float* x = (const float*)d_in[0];
  const float* wq = (const float*)d_in[1];
  const float* bq = (const float*)d_in[2];
  const float* wk = (const float*)d_in[3];
  // bk cancels in softmax
  const float* wv = (const float*)d_in[5];
  const float* bv = (const float*)d_in[6];
  float* out = (float*)d_out;

  char* ws = (char*)d_ws;
  const size_t MB = 1ull << 20;
  // xbf(64MB) | y bf16(64MB) | Ebuf fp8(64MB) | WqT(2) | WkT(2) | Mt(2)
  // | Z: g(4KB) rowsum(128KB) wsum(128KB) xbar(64KB) | vs(128KB)
  unsigned short* xbf = (unsigned short*)(ws);
  unsigned short* y = (unsigned short*)(ws + 64 * MB);
  unsigned char* Ebuf = (unsigned char*)(ws + 128 * MB);
  unsigned short* WqT = (unsigned short*)(ws + 192 * MB);
  unsigned short* WkT = (unsigned short*)(ws + 194 * MB);
  unsigned short* Mt = (unsigned short*)(ws + 196 * MB);
  float* g = (float*)(ws + 198 * MB);
  float* rowsum = g + E_;
  float* wsum = rowsum + B_ * S_;
  float* xbar = wsum + B_ * S_;
  float* vs = xbar + B_ * E_;

  hipMemsetAsync(g, 0, (size_t)(E_ + 2 * B_ * S_ + B_ * E_) * sizeof(float),
                 stream);
  hipMemsetAsync(out, 0, (size_t)B_ * E_ * sizeof(float), stream);

  gvec_kernel<<<dim3(E_ / 256, 32), 256, 0, stream>>>(wk, bq, g);
  cast_x_v_kernel<<<B_ * S_, 256, 0, stream>>>(x, g, xbf, vs);
  tcast_kernel<<<dim3(32, 32), 256, 0, stream>>>(wq, WqT);
  tcast_kernel<<<dim3(32, 32), 256, 0, stream>>>(wk, WkT);

  // Mt[e',e] = Σ_f wk[f,e']·wq[f,e]  (bf16 out)
  gemm_bt<0><<<dim3(8, 8), 256, 0, stream>>>(
      WkT, WqT, (void*)Mt, nullptr, nullptr, 1.0f, E_, E_, E_, E_, 0, 0, 0);
  // y = x·M  (bf16 out)
  gemm_bt<0><<<dim3(E_ / 128, (B_ * S_) / 128), 256, 0, stream>>>(
      xbf, Mt, (void*)y, nullptr, nullptr, 1.0f, E_, E_, E_, E_, 0, 0, 0);
  // e[b,q,k] = exp(y_q·x_k/32 + vs[b,k]) -> fp8 π-permuted; rowsum fp32
  gemm_bt<1><<<dim3(S_ / 128, S_ / 128, B_), 256, 0, stream>>>(
      y, xbf, (void*)Ebuf, vs, rowsum, 0.03125f, E_, E_, E_, S_,
      (long long)S_ * E_, (long long)S_ * E_, (long long)S_ * S_);

  colsum_kernel<<<dim3(S_ / 64, B_), 256, 0, stream>>>(
      (const unsigned int*)Ebuf, rowsum, wsum);
  xbar_kernel<<<dim3(16, B_), 256, 0, stream>>>(xbf, wsum, xbar);
  out_kernel<<<dim3(B_ * E_ / 256, 4), 256, 0, stream>>>(xbar, wv, bv, out);
}